// Round 1
// baseline (1155.589 us; speedup 1.0000x reference)
//
#include <hip/hip_runtime.h>
#include <stdint.h>

#define NSAMP 16384
#define NSITE 2048
#define BM 128
#define BN 128
#define BK 32
#define NTILES_M (NSAMP / BM)  // 128
#define NTILES_N (NSITE / BN)  // 16

typedef __bf16 bf16x8 __attribute__((ext_vector_type(8)));
typedef float f32x4 __attribute__((ext_vector_type(4)));

// round-to-nearest-even f32 -> bf16 bits (manual, avoids header type pitfalls)
__device__ __forceinline__ unsigned short f2bf(float f) {
  unsigned int u = __builtin_bit_cast(unsigned int, f);
  u += 0x7FFFu + ((u >> 16) & 1u);
  return (unsigned short)(u >> 16);
}
__device__ __forceinline__ float bf2f(unsigned short b) {
  unsigned int u = ((unsigned int)b) << 16;
  return __builtin_bit_cast(float, u);
}

__device__ __forceinline__ void gload_lds16(const void* g, void* l) {
  __builtin_amdgcn_global_load_lds(
      (const __attribute__((address_space(1))) void*)g,
      (__attribute__((address_space(3))) void*)l, 16, 0, 0);
}

// W row-major planes: W[j][i] = kernel[j*(j-1)/2 + i] for i<j else 0.
__global__ void build_w_kernel(const float* __restrict__ kern,
                               unsigned short* __restrict__ Wh,
                               unsigned short* __restrict__ Wl) {
  int idx = blockIdx.x * blockDim.x + threadIdx.x;
  int j = idx >> 11;
  int i = idx & (NSITE - 1);
  float v = 0.0f;
  if (i < j) v = kern[j * (j - 1) / 2 + i];
  unsigned short h = f2bf(v);
  Wh[idx] = h;
  Wl[idx] = f2bf(v - bf2f(h));
}

// split x (f32) into hi/lo bf16 planes, 4 elems/thread
__global__ void build_x_kernel(const float* __restrict__ x,
                               unsigned short* __restrict__ Xh,
                               unsigned short* __restrict__ Xl) {
  int idx = blockIdx.x * blockDim.x + threadIdx.x;
  const float4 v = reinterpret_cast<const float4*>(x)[idx];
  float vv[4] = {v.x, v.y, v.z, v.w};
  unsigned short hh[4], ll[4];
#pragma unroll
  for (int e = 0; e < 4; ++e) {
    hh[e] = f2bf(vv[e]);
    ll[e] = f2bf(vv[e] - bf2f(hh[e]));
  }
  reinterpret_cast<ushort4*>(Xh)[idx] = make_ushort4(hh[0], hh[1], hh[2], hh[3]);
  reinterpret_cast<ushort4*>(Xl)[idx] = make_ushort4(ll[0], ll[1], ll[2], ll[3]);
}

// C = A @ W^T (strictly-lower-tri W), split-bf16 x split-bf16, f32 accum.
// EPI=0: write P planes = split_bf16(C * x).  EPI=1: out[row] += sum_col C*x.
template <int EPI>
__global__ __launch_bounds__(256, 2) void gemm_pass(
    const unsigned short* __restrict__ Ah, const unsigned short* __restrict__ Al,
    const unsigned short* __restrict__ Wh, const unsigned short* __restrict__ Wl,
    const float* __restrict__ x,
    unsigned short* __restrict__ Ph, unsigned short* __restrict__ Pl,
    float* __restrict__ out) {
  __shared__ unsigned short sAh[BM * BK];
  __shared__ unsigned short sAl[BM * BK];
  __shared__ unsigned short sBh[BN * BK];  // sB[col][k] == W[n0+col][k0+k]
  __shared__ unsigned short sBl[BN * BK];

  const int bid = blockIdx.x;
  const int nt = bid & (NTILES_N - 1);   // interleave heavy/light column tiles
  const int mt = bid >> 4;
  const int m0 = mt * BM;
  const int n0 = nt * BN;
  const int tid = threadIdx.x;
  const int wid = tid >> 6;
  const int lane = tid & 63;
  const int wm = wid >> 1;
  const int wn = wid & 1;

  f32x4 acc[4][4] = {};

  // strictly lower triangular: columns [n0, n0+BN) need only k < n0+BN
  const int nkt = (n0 + BN) / BK;
  const int rs = wid * 32 + (lane >> 2);  // staging row (this wave's 32-row slice)
  const int cb = (lane & 3) * 16;         // byte offset within 64B row-segment

  for (int kt = 0; kt < nkt; ++kt) {
    const int k0 = kt * BK;
#pragma unroll
    for (int t = 0; t < 2; ++t) {
      const int r = rs + t * 16;
      const int ldso = r * 64 + cb;  // LDS byte offset, == wave base + lane*16
      const size_t goA = (size_t)(m0 + r) * NSITE + k0;
      gload_lds16((const char*)(Ah + goA) + cb, (char*)sAh + ldso);
      gload_lds16((const char*)(Al + goA) + cb, (char*)sAl + ldso);
      const size_t goB = (size_t)(n0 + r) * NSITE + k0;
      gload_lds16((const char*)(Wh + goB) + cb, (char*)sBh + ldso);
      gload_lds16((const char*)(Wl + goB) + cb, (char*)sBl + ldso);
    }
    __syncthreads();

    const int lr = lane & 15;
    const int kq = (lane >> 4) * 8;
    bf16x8 ahf[4], alf[4], bhf[4], blf[4];
#pragma unroll
    for (int i = 0; i < 4; ++i) {
      ahf[i] = *(const bf16x8*)&sAh[(wm * 64 + i * 16 + lr) * BK + kq];
      alf[i] = *(const bf16x8*)&sAl[(wm * 64 + i * 16 + lr) * BK + kq];
      bhf[i] = *(const bf16x8*)&sBh[(wn * 64 + i * 16 + lr) * BK + kq];
      blf[i] = *(const bf16x8*)&sBl[(wn * 64 + i * 16 + lr) * BK + kq];
    }
#pragma unroll
    for (int i = 0; i < 4; ++i)
#pragma unroll
      for (int j = 0; j < 4; ++j) {
        acc[i][j] = __builtin_amdgcn_mfma_f32_16x16x32_bf16(ahf[i], bhf[j], acc[i][j], 0, 0, 0);
        acc[i][j] = __builtin_amdgcn_mfma_f32_16x16x32_bf16(alf[i], bhf[j], acc[i][j], 0, 0, 0);
        acc[i][j] = __builtin_amdgcn_mfma_f32_16x16x32_bf16(ahf[i], blf[j], acc[i][j], 0, 0, 0);
      }
    __syncthreads();
  }

  const int lc = lane & 15;
  const int lq = lane >> 4;
  if (EPI == 0) {
#pragma unroll
    for (int i = 0; i < 4; ++i) {
#pragma unroll
      for (int j = 0; j < 4; ++j) {
#pragma unroll
        for (int r = 0; r < 4; ++r) {
          const int grow = m0 + wm * 64 + i * 16 + lq * 4 + r;
          const int gcol = n0 + wn * 64 + j * 16 + lc;
          const size_t off = (size_t)grow * NSITE + gcol;
          const float p = acc[i][j][r] * x[off];
          const unsigned short h = f2bf(p);
          Ph[off] = h;
          Pl[off] = f2bf(p - bf2f(h));
        }
      }
    }
  } else {
#pragma unroll
    for (int i = 0; i < 4; ++i) {
#pragma unroll
      for (int r = 0; r < 4; ++r) {
        const int grow = m0 + wm * 64 + i * 16 + lq * 4 + r;
        float s = 0.0f;
#pragma unroll
        for (int j = 0; j < 4; ++j) {
          const int gcol = n0 + wn * 64 + j * 16 + lc;
          s += acc[i][j][r] * x[(size_t)grow * NSITE + gcol];
        }
        s += __shfl_xor(s, 1);
        s += __shfl_xor(s, 2);
        s += __shfl_xor(s, 4);
        s += __shfl_xor(s, 8);
        if (lc == 0) atomicAdd(&out[grow], s);
      }
    }
  }
}

extern "C" void kernel_launch(void* const* d_in, const int* in_sizes, int n_in,
                              void* d_out, int out_size, void* d_ws, size_t ws_size,
                              hipStream_t stream) {
  const float* x = (const float*)d_in[0];
  const float* kern = (const float*)d_in[1];
  float* out = (float*)d_out;

  unsigned short* Wh = (unsigned short*)d_ws;                 // N*N
  unsigned short* Wl = Wh + (size_t)NSITE * NSITE;            // N*N
  unsigned short* Xh = Wl + (size_t)NSITE * NSITE;            // NS*N
  unsigned short* Xl = Xh + (size_t)NSAMP * NSITE;
  unsigned short* Ph = Xl + (size_t)NSAMP * NSITE;
  unsigned short* Pl = Ph + (size_t)NSAMP * NSITE;

  hipMemsetAsync(d_out, 0, (size_t)NSAMP * sizeof(float), stream);
  build_w_kernel<<<(NSITE * NSITE) / 256, 256, 0, stream>>>(kern, Wh, Wl);
  build_x_kernel<<<(NSAMP * NSITE / 4) / 256, 256, 0, stream>>>(x, Xh, Xl);

  // pass 1: z1 = x @ W^T ; P = split(z1 * x)
  gemm_pass<0><<<NTILES_M * NTILES_N, 256, 0, stream>>>(Xh, Xl, Wh, Wl, x, Ph, Pl, nullptr);
  // pass 2: z2 = (z1*x) @ W^T ; X <- split(z2 * x)   (x-planes no longer needed)
  gemm_pass<0><<<NTILES_M * NTILES_N, 256, 0, stream>>>(Ph, Pl, Wh, Wl, x, Xh, Xl, nullptr);
  // pass 3: z3 = (z2*x) @ W^T ; out[n] = sum_j z3*x
  gemm_pass<1><<<NTILES_M * NTILES_N, 256, 0, stream>>>(Xh, Xl, Wh, Wl, x, nullptr, nullptr, out);
}

// Round 2
// 1116.895 us; speedup vs baseline: 1.0346x; 1.0346x over previous
//
#include <hip/hip_runtime.h>
#include <stdint.h>

#define NSAMP 16384
#define NSITE 2048
#define BM 256
#define BN 256
#define BK 32
#define NT_M (NSAMP / BM)  // 64
#define NT_N (NSITE / BN)  // 8

typedef __bf16 bf16x8 __attribute__((ext_vector_type(8)));
typedef float f32x4 __attribute__((ext_vector_type(4)));

__device__ __forceinline__ unsigned short f2bf(float f) {
  unsigned int u = __builtin_bit_cast(unsigned int, f);
  u += 0x7FFFu + ((u >> 16) & 1u);
  return (unsigned short)(u >> 16);
}
__device__ __forceinline__ float bf2f(unsigned short b) {
  unsigned int u = ((unsigned int)b) << 16;
  return __builtin_bit_cast(float, u);
}

__device__ __forceinline__ void gload_lds16(const void* g, void* l) {
  __builtin_amdgcn_global_load_lds(
      (const __attribute__((address_space(1))) void*)g,
      (__attribute__((address_space(3))) void*)l, 16, 0, 0);
}

#define SBAR() __builtin_amdgcn_sched_barrier(0)
#define BAR()  do { SBAR(); __builtin_amdgcn_s_barrier(); SBAR(); } while (0)
#define WAITLGKM() do { asm volatile("s_waitcnt lgkmcnt(0)" ::: "memory"); SBAR(); } while (0)
#define WAITVM()   do { asm volatile("s_waitcnt vmcnt(0)" ::: "memory"); SBAR(); } while (0)

__global__ void build_w_kernel(const float* __restrict__ kern,
                               unsigned short* __restrict__ Wh,
                               unsigned short* __restrict__ Wl) {
  int idx = blockIdx.x * blockDim.x + threadIdx.x;
  int j = idx >> 11;
  int i = idx & (NSITE - 1);
  float v = 0.0f;
  if (i < j) v = kern[j * (j - 1) / 2 + i];
  unsigned short h = f2bf(v);
  Wh[idx] = h;
  Wl[idx] = f2bf(v - bf2f(h));
}

__global__ void build_x_kernel(const float* __restrict__ x,
                               unsigned short* __restrict__ Xh,
                               unsigned short* __restrict__ Xl) {
  int idx = blockIdx.x * blockDim.x + threadIdx.x;
  const float4 v = reinterpret_cast<const float4*>(x)[idx];
  float vv[4] = {v.x, v.y, v.z, v.w};
  unsigned short hh[4], ll[4];
#pragma unroll
  for (int e = 0; e < 4; ++e) {
    hh[e] = f2bf(vv[e]);
    ll[e] = f2bf(vv[e] - bf2f(hh[e]));
  }
  reinterpret_cast<ushort4*>(Xh)[idx] = make_ushort4(hh[0], hh[1], hh[2], hh[3]);
  reinterpret_cast<ushort4*>(Xl)[idx] = make_ushort4(ll[0], ll[1], ll[2], ll[3]);
}

// 256x256 tile, 8 waves (2Mx4N), BK=32, 4-phase schedule, XOR-swizzled LDS.
// 3-MFMA split-bf16 product (ah*bh + al*bh + ah*bl), f32 accum.
template <int EPI>
__global__ __launch_bounds__(512, 2) void gemm_pass(
    const unsigned short* __restrict__ Ah, const unsigned short* __restrict__ Al,
    const unsigned short* __restrict__ Wh, const unsigned short* __restrict__ Wl,
    const float* __restrict__ x,
    unsigned short* __restrict__ Ph, unsigned short* __restrict__ Pl,
    float* __restrict__ out) {
  // [buf][plane: Ah Al Bh Bl][256*32], 128 KiB total
  __shared__ unsigned short lds[2][4][BM * BK];

  const int bid = blockIdx.x;
  const int b3 = (bid >> 3) & 7;
  const int nt = (b3 & 1) ? (7 - (b3 >> 1)) : (b3 >> 1);  // {0,7,1,6,2,5,3,4}
  const int mt = ((bid >> 6) << 3) | (bid & 7);
  const int m0 = mt * BM;
  const int n0 = nt * BN;
  const int tid = threadIdx.x;
  const int lane = tid & 63;
  const int wid = tid >> 6;
  const int wm = wid >> 2;   // 0..1
  const int wn = wid & 3;    // 0..3
  const int lr = lane & 15;
  const int qq = lane >> 4;  // 0..3

  f32x4 acc[8][4] = {};
  bf16x8 fah[4], fal[4], fbh[4], fbl[4];

  const int nkt = (n0 + BN) / BK;  // 8*(nt+1), strictly-lower-tri K cut
  const int srow = tid >> 2;       // 0..127
  const int schunk = tid & 3;

  const unsigned short* gbase[4] = {Ah, Al, Wh, Wl};

  auto STAGE = [&](int kt1, int buf) {
    const int k0 = kt1 * BK;
#pragma unroll
    for (int p = 0; p < 4; ++p) {
      const unsigned short* gp = gbase[p];
      const int rb = (p < 2) ? m0 : n0;
#pragma unroll
      for (int c = 0; c < 2; ++c) {
        const int row = c * 128 + srow;
        const int gch = schunk ^ ((row >> 1) & 3);  // inverse swizzle on source
        const char* src = (const char*)(gp + (size_t)(rb + row) * NSITE + k0) + gch * 16;
        char* dst = (char*)&lds[buf][p][0] + c * 8192 + tid * 16;  // linear dest
        gload_lds16(src, dst);
      }
    }
  };

  auto LDA = [&](int half, int buf) {
#pragma unroll
    for (int i = 0; i < 4; ++i) {
      const int row = wm * 128 + (half * 4 + i) * 16 + lr;
      const int byte = row * 64 + ((qq ^ ((row >> 1) & 3)) << 4);  // swizzled read
      fah[i] = *(const bf16x8*)((const char*)&lds[buf][0][0] + byte);
      fal[i] = *(const bf16x8*)((const char*)&lds[buf][1][0] + byte);
    }
  };
  auto LDB = [&](int half, int buf) {
#pragma unroll
    for (int j = 0; j < 2; ++j) {
      const int row = wn * 64 + (half * 2 + j) * 16 + lr;
      const int byte = row * 64 + ((qq ^ ((row >> 1) & 3)) << 4);
      fbh[half * 2 + j] = *(const bf16x8*)((const char*)&lds[buf][2][0] + byte);
      fbl[half * 2 + j] = *(const bf16x8*)((const char*)&lds[buf][3][0] + byte);
    }
  };

#define MM(AH, J0)                                                                         \
  do {                                                                                     \
    _Pragma("unroll") for (int i = 0; i < 4; ++i) _Pragma("unroll") for (int j = 0; j < 2; \
                                                                         ++j)              \
        acc[(AH)*4 + i][(J0) + j] = __builtin_amdgcn_mfma_f32_16x16x32_bf16(               \
            fah[i], fbh[(J0) + j], acc[(AH)*4 + i][(J0) + j], 0, 0, 0);                    \
    _Pragma("unroll") for (int i = 0; i < 4; ++i) _Pragma("unroll") for (int j = 0; j < 2; \
                                                                         ++j)              \
        acc[(AH)*4 + i][(J0) + j] = __builtin_amdgcn_mfma_f32_16x16x32_bf16(               \
            fal[i], fbh[(J0) + j], acc[(AH)*4 + i][(J0) + j], 0, 0, 0);                    \
    _Pragma("unroll") for (int i = 0; i < 4; ++i) _Pragma("unroll") for (int j = 0; j < 2; \
                                                                         ++j)              \
        acc[(AH)*4 + i][(J0) + j] = __builtin_amdgcn_mfma_f32_16x16x32_bf16(               \
            fah[i], fbl[(J0) + j], acc[(AH)*4 + i][(J0) + j], 0, 0, 0);                    \
  } while (0)

  // prologue: stage K-step 0 into buf 0
  STAGE(0, 0);
  WAITVM();
  BAR();

  for (int kt = 0; kt < nkt; ++kt) {
    const int cur = kt & 1;
    // ---- P0: read A-half0 + B-half0; issue all next-step stages
    LDA(0, cur);
    LDB(0, cur);
    if (kt + 1 < nkt) STAGE(kt + 1, cur ^ 1);
    BAR();
    WAITLGKM();
    __builtin_amdgcn_s_setprio(1);
    MM(0, 0);
    __builtin_amdgcn_s_setprio(0);
    BAR();
    // ---- P1: read B-half1
    LDB(1, cur);
    BAR();
    WAITLGKM();
    __builtin_amdgcn_s_setprio(1);
    MM(0, 2);
    __builtin_amdgcn_s_setprio(0);
    BAR();
    // ---- P2: read A-half1
    LDA(1, cur);
    BAR();
    WAITLGKM();
    __builtin_amdgcn_s_setprio(1);
    MM(1, 2);
    __builtin_amdgcn_s_setprio(0);
    BAR();
    // ---- P3: no reads (B-half0 still resident); drain stages, flip
    __builtin_amdgcn_s_setprio(1);
    MM(1, 0);
    __builtin_amdgcn_s_setprio(0);
    WAITVM();
    BAR();
  }

  const int lq = qq;
  if (EPI == 0) {
#pragma unroll
    for (int i = 0; i < 8; ++i) {
#pragma unroll
      for (int j = 0; j < 4; ++j) {
#pragma unroll
        for (int r = 0; r < 4; ++r) {
          const int grow = m0 + wm * 128 + i * 16 + lq * 4 + r;
          const int gcol = n0 + wn * 64 + j * 16 + lr;
          const size_t off = (size_t)grow * NSITE + gcol;
          const float p = acc[i][j][r] * x[off];
          const unsigned short h = f2bf(p);
          Ph[off] = h;
          Pl[off] = f2bf(p - bf2f(h));
        }
      }
    }
  } else {
#pragma unroll
    for (int i = 0; i < 8; ++i) {
#pragma unroll
      for (int r = 0; r < 4; ++r) {
        const int grow = m0 + wm * 128 + i * 16 + lq * 4 + r;
        float s = 0.0f;
#pragma unroll
        for (int j = 0; j < 4; ++j) {
          const int gcol = n0 + wn * 64 + j * 16 + lr;
          s += acc[i][j][r] * x[(size_t)grow * NSITE + gcol];
        }
        s += __shfl_xor(s, 1);
        s += __shfl_xor(s, 2);
        s += __shfl_xor(s, 4);
        s += __shfl_xor(s, 8);
        if (lr == 0) atomicAdd(&out[grow], s);
      }
    }
  }
#undef MM
}

extern "C" void kernel_launch(void* const* d_in, const int* in_sizes, int n_in,
                              void* d_out, int out_size, void* d_ws, size_t ws_size,
                              hipStream_t stream) {
  const float* x = (const float*)d_in[0];
  const float* kern = (const float*)d_in[1];
  float* out = (float*)d_out;

  unsigned short* Wh = (unsigned short*)d_ws;                 // N*N
  unsigned short* Wl = Wh + (size_t)NSITE * NSITE;            // N*N
  unsigned short* Xh = Wl + (size_t)NSITE * NSITE;            // NS*N
  unsigned short* Xl = Xh + (size_t)NSAMP * NSITE;
  unsigned short* Ph = Xl + (size_t)NSAMP * NSITE;
  unsigned short* Pl = Ph + (size_t)NSAMP * NSITE;

  hipMemsetAsync(d_out, 0, (size_t)NSAMP * sizeof(float), stream);
  build_w_kernel<<<(NSITE * NSITE) / 256, 256, 0, stream>>>(kern, Wh, Wl);
  build_x_kernel<<<(NSAMP * NSITE / 4) / 256, 256, 0, stream>>>(x, Xh, Xl);

  // pass 1: z1 = x @ W^T ; P = split(z1 * x)
  gemm_pass<0><<<NT_M * NT_N, 512, 0, stream>>>(Xh, Xl, Wh, Wl, x, Ph, Pl, nullptr);
  // pass 2: z2 = (z1*x) @ W^T ; X <- split(z2 * x)
  gemm_pass<0><<<NT_M * NT_N, 512, 0, stream>>>(Ph, Pl, Wh, Wl, x, Xh, Xl, nullptr);
  // pass 3: z3 = (z2*x) @ W^T ; out[n] = sum_j z3*x
  gemm_pass<1><<<NT_M * NT_N, 512, 0, stream>>>(Xh, Xl, Wh, Wl, x, nullptr, nullptr, out);
}

// Round 3
// 947.674 us; speedup vs baseline: 1.2194x; 1.1786x over previous
//
#include <hip/hip_runtime.h>
#include <stdint.h>

#define NSAMP 16384
#define NSITE 2048
#define BM 256
#define BN 256
#define BK 32
#define NT_M (NSAMP / BM)  // 64
#define NT_N (NSITE / BN)  // 8

typedef __bf16 bf16x8 __attribute__((ext_vector_type(8)));
typedef float f32x4 __attribute__((ext_vector_type(4)));

__device__ __forceinline__ unsigned short f2bf(float f) {
  unsigned int u = __builtin_bit_cast(unsigned int, f);
  u += 0x7FFFu + ((u >> 16) & 1u);
  return (unsigned short)(u >> 16);
}
__device__ __forceinline__ float bf2f(unsigned short b) {
  unsigned int u = ((unsigned int)b) << 16;
  return __builtin_bit_cast(float, u);
}

__device__ __forceinline__ void gload_lds16(const void* g, void* l) {
  __builtin_amdgcn_global_load_lds(
      (const __attribute__((address_space(1))) void*)g,
      (__attribute__((address_space(3))) void*)l, 16, 0, 0);
}

#define SBAR() __builtin_amdgcn_sched_barrier(0)
#define BAR()  do { SBAR(); __builtin_amdgcn_s_barrier(); SBAR(); } while (0)
#define WLGKM(N) do { asm volatile("s_waitcnt lgkmcnt(" #N ")" ::: "memory"); SBAR(); } while (0)
#define WVM(N)   do { asm volatile("s_waitcnt vmcnt(" #N ")" ::: "memory"); SBAR(); } while (0)

__global__ void build_w_kernel(const float* __restrict__ kern,
                               unsigned short* __restrict__ Wh,
                               unsigned short* __restrict__ Wl) {
  int idx = blockIdx.x * blockDim.x + threadIdx.x;
  int j = idx >> 11;
  int i = idx & (NSITE - 1);
  float v = 0.0f;
  if (i < j) v = kern[j * (j - 1) / 2 + i];
  unsigned short h = f2bf(v);
  Wh[idx] = h;
  Wl[idx] = f2bf(v - bf2f(h));
}

__global__ void build_x_kernel(const float* __restrict__ x,
                               unsigned short* __restrict__ Xh,
                               unsigned short* __restrict__ Xl) {
  int idx = blockIdx.x * blockDim.x + threadIdx.x;
  const float4 v = reinterpret_cast<const float4*>(x)[idx];
  float vv[4] = {v.x, v.y, v.z, v.w};
  unsigned short hh[4], ll[4];
#pragma unroll
  for (int e = 0; e < 4; ++e) {
    hh[e] = f2bf(vv[e]);
    ll[e] = f2bf(vv[e] - bf2f(hh[e]));
  }
  reinterpret_cast<ushort4*>(Xh)[idx] = make_ushort4(hh[0], hh[1], hh[2], hh[3]);
  reinterpret_cast<ushort4*>(Xl)[idx] = make_ushort4(ll[0], ll[1], ll[2], ll[3]);
}

// 256x256 tile, 8 waves (2Mx4N), BK=32.
// LDS = ring of 5 half-tile slots (32 KiB each: 4 planes x 128 rows x 32k).
// Counted-vmcnt pipeline: halves 2t,2t+1 consumed at step t; halves 2t+3,2t+4
// staged at step t; end-of-step wait = vmcnt(4). One barrier per K-step.
// 3-MFMA split-bf16 product (ah*bh + al*bh + ah*bl), f32 accum.
template <int EPI>
__global__ __launch_bounds__(512, 2) void gemm_pass(
    const unsigned short* __restrict__ Ah, const unsigned short* __restrict__ Al,
    const unsigned short* __restrict__ Wh, const unsigned short* __restrict__ Wl,
    const float* __restrict__ x,
    unsigned short* __restrict__ Ph, unsigned short* __restrict__ Pl,
    float* __restrict__ out) {
  __shared__ unsigned short lds[5][4][128 * BK];  // 5 x 4 x 8 KiB = 160 KiB

  const int bid = blockIdx.x;
  const int b3 = (bid >> 3) & 7;
  const int nt = (b3 & 1) ? (7 - (b3 >> 1)) : (b3 >> 1);  // {0,7,1,6,2,5,3,4}
  const int mt = ((bid >> 6) << 3) | (bid & 7);
  const int m0 = mt * BM;
  const int n0 = nt * BN;
  const int tid = threadIdx.x;
  const int lane = tid & 63;
  const int wid = tid >> 6;
  const int wm = wid >> 2;   // 0..1   (A half = wm)
  const int wn = wid & 3;    // 0..3   (B half = wn>>1)
  const int lr = lane & 15;
  const int qq = lane >> 4;  // 0..3
  const int srow = tid >> 2; // 0..127 staging row within half
  const int schunk = tid & 3;
  const int swz = (qq ^ ((lr >> 1) & 3)) << 4;  // read-side XOR swizzle byte off

  f32x4 acc[8][4] = {};
  bf16x8 fbh[4], fbl[4];
  bf16x8 cah[2][2], cal[2][2];  // A frags, double-buffered by chunk parity

  const int nkt = (n0 + BN) / BK;  // strictly-lower-tri K cut (8..64)
  const unsigned short* gbase[4] = {Ah, Al, Wh, Wl};

  // stage one half-tile (4 planes x 128 rows) of K-step kidx into slot
  auto STAGEH = [&](int slot, int rhalf, int kidx) {
    const int k0 = kidx * BK;
    const int gch = schunk ^ ((srow >> 1) & 3);  // inverse swizzle on source
#pragma unroll
    for (int p = 0; p < 4; ++p) {
      const unsigned short* gp = gbase[p];
      const int rb = (p < 2) ? m0 : n0;
      const char* src =
          (const char*)(gp + (size_t)(rb + rhalf * 128 + srow) * NSITE + k0) + gch * 16;
      char* dst = (char*)&lds[slot][p][0] + tid * 16;  // linear dest
      gload_lds16(src, dst);
    }
  };

  int sA = wm;        // slot of this wave's A half (advances +2 mod 5)
  int sB = wn >> 1;   // slot of this wave's B half
  int s3 = 3, s4 = 4; // slots for halves 2t+3, 2t+4

  auto LDBf = [&]() {
#pragma unroll
    for (int j = 0; j < 4; ++j) {
      const int row = (wn & 1) * 64 + j * 16 + lr;
      const int byte = row * 64 + swz;
      fbh[j] = *(const bf16x8*)((const char*)&lds[sB][2][0] + byte);
      fbl[j] = *(const bf16x8*)((const char*)&lds[sB][3][0] + byte);
    }
  };
  auto LDAc = [&](int i) {  // chunk i: m-blocks 2i, 2i+1 (4 ds_reads)
    const int par = i & 1;
#pragma unroll
    for (int mm = 0; mm < 2; ++mm) {
      const int row = (2 * i + mm) * 16 + lr;  // 0..127 within A half
      const int byte = row * 64 + swz;
      cah[par][mm] = *(const bf16x8*)((const char*)&lds[sA][0][0] + byte);
      cal[par][mm] = *(const bf16x8*)((const char*)&lds[sA][1][0] + byte);
    }
  };
  auto MMc = [&](int i) {  // 24 MFMAs for chunk i
    const int par = i & 1;
#pragma unroll
    for (int t3 = 0; t3 < 3; ++t3)
#pragma unroll
      for (int mm = 0; mm < 2; ++mm)
#pragma unroll
        for (int j = 0; j < 4; ++j) {
          const bf16x8 a = (t3 == 1) ? cal[par][mm] : cah[par][mm];
          const bf16x8 b = (t3 == 2) ? fbl[j] : fbh[j];
          acc[2 * i + mm][j] =
              __builtin_amdgcn_mfma_f32_16x16x32_bf16(a, b, acc[2 * i + mm][j], 0, 0, 0);
        }
  };

  // prologue: stage halves 0,1,2
  STAGEH(0, 0, 0);
  STAGEH(1, 1, 0);
  STAGEH(2, 0, 1);
  WVM(4);   // halves 0,1 landed (half 2 may still fly)
  BAR();

  for (int t = 0; t < nkt; ++t) {
    LDBf();                              // 8 ds_read_b128
    LDAc(0);                             // 4
    if (t < nkt - 1) STAGEH(s3, 1, t + 1);  // half 2t+3 (4 gload_lds)
    if (t < nkt - 2) STAGEH(s4, 0, t + 2);  // half 2t+4
    LDAc(1);                             // 4  (lgkm outstanding 16)
    WLGKM(4);                            // LDB + chunk0 done
    __builtin_amdgcn_s_setprio(1);
    MMc(0);
    LDAc(2);
    WLGKM(4);                            // chunk1 done
    MMc(1);
    LDAc(3);
    WLGKM(4);                            // chunk2 done
    MMc(2);
    WLGKM(0);                            // chunk3 done
    MMc(3);
    __builtin_amdgcn_s_setprio(0);
    sA += 2; if (sA >= 5) sA -= 5;
    sB += 2; if (sB >= 5) sB -= 5;
    s3 += 2; if (s3 >= 5) s3 -= 5;
    s4 += 2; if (s4 >= 5) s4 -= 5;
    if (t < nkt - 1) {
      if (t < nkt - 2) { WVM(4); } else { WVM(0); }  // next step's halves landed
      BAR();
    }
  }

  const int lq = qq;
  if (EPI == 0) {
#pragma unroll
    for (int i = 0; i < 8; ++i) {
#pragma unroll
      for (int j = 0; j < 4; ++j) {
#pragma unroll
        for (int r = 0; r < 4; ++r) {
          const int grow = m0 + wm * 128 + i * 16 + lq * 4 + r;
          const int gcol = n0 + wn * 64 + j * 16 + lr;
          const size_t off = (size_t)grow * NSITE + gcol;
          const float p = acc[i][j][r] * x[off];
          const unsigned short h = f2bf(p);
          Ph[off] = h;
          Pl[off] = f2bf(p - bf2f(h));
        }
      }
    }
  } else {
#pragma unroll
    for (int i = 0; i < 8; ++i) {
#pragma unroll
      for (int r = 0; r < 4; ++r) {
        const int grow = m0 + wm * 128 + i * 16 + lq * 4 + r;
        float s = 0.0f;
#pragma unroll
        for (int j = 0; j < 4; ++j) {
          const int gcol = n0 + wn * 64 + j * 16 + lr;
          s += acc[i][j][r] * x[(size_t)grow * NSITE + gcol];
        }
        s += __shfl_xor(s, 1);
        s += __shfl_xor(s, 2);
        s += __shfl_xor(s, 4);
        s += __shfl_xor(s, 8);
        if (lr == 0) atomicAdd(&out[grow], s);
      }
    }
  }
}

extern "C" void kernel_launch(void* const* d_in, const int* in_sizes, int n_in,
                              void* d_out, int out_size, void* d_ws, size_t ws_size,
                              hipStream_t stream) {
  const float* x = (const float*)d_in[0];
  const float* kern = (const float*)d_in[1];
  float* out = (float*)d_out;

  unsigned short* Wh = (unsigned short*)d_ws;                 // N*N
  unsigned short* Wl = Wh + (size_t)NSITE * NSITE;            // N*N
  unsigned short* Xh = Wl + (size_t)NSITE * NSITE;            // NS*N
  unsigned short* Xl = Xh + (size_t)NSAMP * NSITE;
  unsigned short* Ph = Xl + (size_t)NSAMP * NSITE;
  unsigned short* Pl = Ph + (size_t)NSAMP * NSITE;

  hipMemsetAsync(d_out, 0, (size_t)NSAMP * sizeof(float), stream);
  build_w_kernel<<<(NSITE * NSITE) / 256, 256, 0, stream>>>(kern, Wh, Wl);
  build_x_kernel<<<(NSAMP * NSITE / 4) / 256, 256, 0, stream>>>(x, Xh, Xl);

  // pass 1: z1 = x @ W^T ; P = split(z1 * x)
  gemm_pass<0><<<NT_M * NT_N, 512, 0, stream>>>(Xh, Xl, Wh, Wl, x, Ph, Pl, nullptr);
  // pass 2: z2 = (z1*x) @ W^T ; X <- split(z2 * x)
  gemm_pass<0><<<NT_M * NT_N, 512, 0, stream>>>(Ph, Pl, Wh, Wl, x, Xh, Xl, nullptr);
  // pass 3: z3 = (z2*x) @ W^T ; out[n] = sum_j z3*x
  gemm_pass<1><<<NT_M * NT_N, 512, 0, stream>>>(Xh, Xl, Wh, Wl, x, nullptr, nullptr, out);
}

// Round 4
// 627.858 us; speedup vs baseline: 1.8405x; 1.5094x over previous
//
#include <hip/hip_runtime.h>
#include <stdint.h>

#define NSAMP 16384
#define NSITE 2048
#define BM 256
#define BN 256
#define BK 32
#define NT_M (NSAMP / BM)  // 64
#define NT_N (NSITE / BN)  // 8

typedef __bf16 bf16x8 __attribute__((ext_vector_type(8)));
typedef float f32x16 __attribute__((ext_vector_type(16)));

__device__ __forceinline__ unsigned short f2bf(float f) {
  unsigned int u = __builtin_bit_cast(unsigned int, f);
  u += 0x7FFFu + ((u >> 16) & 1u);
  return (unsigned short)(u >> 16);
}
__device__ __forceinline__ float bf2f(unsigned short b) {
  unsigned int u = ((unsigned int)b) << 16;
  return __builtin_bit_cast(float, u);
}

__device__ __forceinline__ void gload_lds16(const void* g, void* l) {
  __builtin_amdgcn_global_load_lds(
      (const __attribute__((address_space(1))) void*)g,
      (__attribute__((address_space(3))) void*)l, 16, 0, 0);
}

#define SBAR() __builtin_amdgcn_sched_barrier(0)
#define BAR()  do { SBAR(); __builtin_amdgcn_s_barrier(); SBAR(); } while (0)
#define WLGKM(N) do { asm volatile("s_waitcnt lgkmcnt(" #N ")" ::: "memory"); SBAR(); } while (0)
#define WVM(N)   do { asm volatile("s_waitcnt vmcnt(" #N ")" ::: "memory"); SBAR(); } while (0)

// single-plane bf16 W: W[j][i] = bf16(kernel[tri(j,i)]) for i<j else 0
__global__ void build_w_kernel(const float* __restrict__ kern,
                               unsigned short* __restrict__ W) {
  int idx = blockIdx.x * blockDim.x + threadIdx.x;
  int j = idx >> 11;
  int i = idx & (NSITE - 1);
  float v = 0.0f;
  if (i < j) v = kern[j * (j - 1) / 2 + i];
  W[idx] = f2bf(v);
}

__global__ void build_x_kernel(const float* __restrict__ x,
                               unsigned short* __restrict__ Xh,
                               unsigned short* __restrict__ Xl) {
  int idx = blockIdx.x * blockDim.x + threadIdx.x;
  const float4 v = reinterpret_cast<const float4*>(x)[idx];
  float vv[4] = {v.x, v.y, v.z, v.w};
  unsigned short hh[4], ll[4];
#pragma unroll
  for (int e = 0; e < 4; ++e) {
    hh[e] = f2bf(vv[e]);
    ll[e] = f2bf(vv[e] - bf2f(hh[e]));
  }
  reinterpret_cast<ushort4*>(Xh)[idx] = make_ushort4(hh[0], hh[1], hh[2], hh[3]);
  reinterpret_cast<ushort4*>(Xl)[idx] = make_ushort4(ll[0], ll[1], ll[2], ll[3]);
}

// 256x256 tile, 8 waves (2Mx4N), BK=32, 32x32x16 MFMA.
// A split-bf16 (2 planes), W single-plane bf16: 2 MFMAs per product.
// LDS ring of 6 slots x 24KB (3 planes x 128 rows x 64B) = 144 KiB.
// Step t consumes halves 2t,2t+1; stages 2t+4,2t+5; steady wait vmcnt(6).
template <int EPI>
__global__ __launch_bounds__(512, 2) void gemm_pass(
    const unsigned short* __restrict__ Ah, const unsigned short* __restrict__ Al,
    const unsigned short* __restrict__ W, const float* __restrict__ x,
    unsigned short* __restrict__ Ph, unsigned short* __restrict__ Pl,
    float* __restrict__ out) {
  __shared__ unsigned short lds[6][3][128 * BK];  // 147456 B

  const int bid = blockIdx.x;
  // makespan-optimal triangular order: round1 nt=7..4, round2 nt=3..0
  const int rnd = bid >> 8;
  const int idx = bid & 255;
  const int cohort = idx >> 6;
  const int mt = idx & 63;
  const int nt = rnd ? (3 - cohort) : (7 - cohort);
  const int m0 = mt * BM;
  const int n0 = nt * BN;

  const int tid = threadIdx.x;
  const int lane = tid & 63;
  const int wid = tid >> 6;
  const int wm = wid >> 2;   // 0..1: A half (rows wm*128..)
  const int wn = wid & 3;    // 0..3: B cols wn*64.. (B half = wn>>1)
  const int l32 = lane & 31;
  const int hi2 = lane >> 5;  // 0..1
  const int swzl = (l32 >> 1) & 3;
  const int srow = tid >> 2;  // staging row 0..127
  const int gch = (tid & 3) ^ ((srow >> 1) & 3);  // pre-swizzled source chunk

  f32x16 acc[4][2] = {};       // [mb][nb], 128 VGPRs
  bf16x8 fah[2][2], fal[2][2]; // [chunk-parity][mm]
  bf16x8 fb[2][2];             // [kh][nb]

  const int nkt = (n0 + BN) / BK;  // 8*(nt+1)
  const unsigned short* gbase[3] = {Ah, Al, W};
  char* Lb = (char*)&lds[0][0][0];

  auto STAGEH = [&](int slot, int rhalf, int kidx) {
#pragma unroll
    for (int p = 0; p < 3; ++p) {
      const int rb = (p < 2) ? m0 : n0;
      const char* src =
          (const char*)(gbase[p] + (size_t)(rb + rhalf * 128 + srow) * NSITE + kidx * BK) +
          gch * 16;
      gload_lds16(src, Lb + slot * 24576 + p * 8192 + tid * 16);
    }
  };

  int sA = wm;        // slot of this wave's A half
  int sB = wn >> 1;   // slot of this wave's B half
  int s4 = 4, s5 = 5; // staging slots for halves 2t+4, 2t+5

  auto LDA = [&](int kh, int chunk) {  // 4 ds_read_b128
    const int offk = (((kh << 1) + hi2) ^ swzl) << 4;
#pragma unroll
    for (int mm = 0; mm < 2; ++mm) {
      const int rowb = ((chunk * 2 + mm) * 32 + l32) * 64;
      fah[chunk][mm] = *(const bf16x8*)(Lb + sA * 24576 + rowb + offk);
      fal[chunk][mm] = *(const bf16x8*)(Lb + sA * 24576 + 8192 + rowb + offk);
    }
  };
  auto LDB = [&](int kh) {  // 2 ds_read_b128
    const int offk = (((kh << 1) + hi2) ^ swzl) << 4;
#pragma unroll
    for (int nb = 0; nb < 2; ++nb) {
      const int rowb = ((wn & 1) * 64 + nb * 32 + l32) * 64;
      fb[kh][nb] = *(const bf16x8*)(Lb + sB * 24576 + 16384 + rowb + offk);
    }
  };
  auto MM = [&](int kh, int chunk) {  // 8 MFMA (2mb x 2nb x {ah,al})
#pragma unroll
    for (int mm = 0; mm < 2; ++mm)
#pragma unroll
      for (int nb = 0; nb < 2; ++nb) {
        const int mb = chunk * 2 + mm;
        acc[mb][nb] = __builtin_amdgcn_mfma_f32_32x32x16_bf16(fah[chunk][mm], fb[kh][nb],
                                                              acc[mb][nb], 0, 0, 0);
        acc[mb][nb] = __builtin_amdgcn_mfma_f32_32x32x16_bf16(fal[chunk][mm], fb[kh][nb],
                                                              acc[mb][nb], 0, 0, 0);
      }
  };

  // prologue: stage halves 0..3 into slots 0..3
  STAGEH(0, 0, 0);
  STAGEH(1, 1, 0);
  STAGEH(2, 0, 1);
  STAGEH(3, 1, 1);
  WVM(6);  // halves 0,1 landed
  BAR();

  for (int t = 0; t < nkt; ++t) {
    LDB(0);                                   // 2   (lgkm 2)
    LDA(0, 0);                                // 4   (6)
    if (2 * t + 4 < 2 * nkt) STAGEH(s4, 0, t + 2);
    if (2 * t + 5 < 2 * nkt) STAGEH(s5, 1, t + 2);
    LDA(0, 1);                                // 4   (10)
    WLGKM(4);                                 // fb0 + chunk0 ready
    __builtin_amdgcn_s_setprio(1);
    MM(0, 0);
    LDB(1);                                   // 2   (4+2=6)
    LDA(1, 0);                                // 4   (10)
    WLGKM(6);                                 // chunk1(kh0) ready
    MM(0, 1);
    LDA(1, 1);                                // 4   (10)
    WLGKM(4);                                 // fb1 + chunk0(kh1) ready
    MM(1, 0);
    WLGKM(0);                                 // chunk1(kh1) ready
    MM(1, 1);
    __builtin_amdgcn_s_setprio(0);
    sA += 2; if (sA >= 6) sA -= 6;
    sB += 2; if (sB >= 6) sB -= 6;
    s4 += 2; if (s4 >= 6) s4 -= 6;
    s5 += 2; if (s5 >= 6) s5 -= 6;
    if (t + 2 < nkt) { WVM(6); } else { WVM(0); }  // halves <=2t+3 landed
    if (t + 1 < nkt) BAR();
  }

  // epilogue: C/D layout 32x32: col = lane&31, row = (reg&3)+8*(reg>>2)+4*(lane>>5)
  if (EPI == 0) {
#pragma unroll
    for (int mb = 0; mb < 4; ++mb)
#pragma unroll
      for (int nb = 0; nb < 2; ++nb)
#pragma unroll
        for (int reg = 0; reg < 16; ++reg) {
          const int row = (reg & 3) + 8 * (reg >> 2) + 4 * hi2;
          const int grow = m0 + wm * 128 + mb * 32 + row;
          const int gcol = n0 + wn * 64 + nb * 32 + l32;
          const size_t off = (size_t)grow * NSITE + gcol;
          const float p = acc[mb][nb][reg] * x[off];
          const unsigned short h = f2bf(p);
          Ph[off] = h;
          Pl[off] = f2bf(p - bf2f(h));
        }
  } else {
#pragma unroll
    for (int mb = 0; mb < 4; ++mb)
#pragma unroll
      for (int reg = 0; reg < 16; ++reg) {
        const int row = (reg & 3) + 8 * (reg >> 2) + 4 * hi2;
        const int grow = m0 + wm * 128 + mb * 32 + row;
        const int gcol0 = n0 + wn * 64 + l32;
        float s = acc[mb][0][reg] * x[(size_t)grow * NSITE + gcol0] +
                  acc[mb][1][reg] * x[(size_t)grow * NSITE + gcol0 + 32];
        s += __shfl_xor(s, 1);
        s += __shfl_xor(s, 2);
        s += __shfl_xor(s, 4);
        s += __shfl_xor(s, 8);
        s += __shfl_xor(s, 16);
        if (l32 == 0) atomicAdd(&out[grow], s);
      }
  }
}

extern "C" void kernel_launch(void* const* d_in, const int* in_sizes, int n_in,
                              void* d_out, int out_size, void* d_ws, size_t ws_size,
                              hipStream_t stream) {
  const float* x = (const float*)d_in[0];
  const float* kern = (const float*)d_in[1];
  float* out = (float*)d_out;

  unsigned short* W  = (unsigned short*)d_ws;                 // N*N
  unsigned short* Xh = W + (size_t)NSITE * NSITE;             // NS*N
  unsigned short* Xl = Xh + (size_t)NSAMP * NSITE;
  unsigned short* Ph = Xl + (size_t)NSAMP * NSITE;
  unsigned short* Pl = Ph + (size_t)NSAMP * NSITE;

  hipMemsetAsync(d_out, 0, (size_t)NSAMP * sizeof(float), stream);
  build_w_kernel<<<(NSITE * NSITE) / 256, 256, 0, stream>>>(kern, W);
  build_x_kernel<<<(NSAMP * NSITE / 4) / 256, 256, 0, stream>>>(x, Xh, Xl);

  // pass 1: z1 = x @ W^T ; P = split(z1 * x)
  gemm_pass<0><<<NT_M * NT_N, 512, 0, stream>>>(Xh, Xl, W, x, Ph, Pl, nullptr);
  // pass 2: z2 = (z1*x) @ W^T ; X <- split(z2 * x)
  gemm_pass<0><<<NT_M * NT_N, 512, 0, stream>>>(Ph, Pl, W, x, Xh, Xl, nullptr);
  // pass 3: z3 = (z2*x) @ W^T ; out[n] = sum_j z3*x
  gemm_pass<1><<<NT_M * NT_N, 512, 0, stream>>>(Xh, Xl, W, x, nullptr, nullptr, out);
}

// Round 5
// 417.043 us; speedup vs baseline: 2.7709x; 1.5055x over previous
//
#include <hip/hip_runtime.h>
#include <stdint.h>

#define NSAMP 16384
#define NSITE 2048
#define BM 128
#define BN 128
#define BK 32
#define NT_M (NSAMP / BM)  // 128
#define NT_N (NSITE / BN)  // 16

typedef _Float16 f16x8 __attribute__((ext_vector_type(8)));
typedef float f32x16 __attribute__((ext_vector_type(16)));

__device__ __forceinline__ unsigned short f2h(float f) {
  _Float16 h = (_Float16)f;
  return __builtin_bit_cast(unsigned short, h);
}

__device__ __forceinline__ void gload_lds16(const void* g, void* l) {
  __builtin_amdgcn_global_load_lds(
      (const __attribute__((address_space(1))) void*)g,
      (__attribute__((address_space(3))) void*)l, 16, 0, 0);
}

#define SBAR() __builtin_amdgcn_sched_barrier(0)
#define BAR()  do { SBAR(); __builtin_amdgcn_s_barrier(); SBAR(); } while (0)
#define WLGKM(N) do { asm volatile("s_waitcnt lgkmcnt(" #N ")" ::: "memory"); SBAR(); } while (0)
#define WVM(N)   do { asm volatile("s_waitcnt vmcnt(" #N ")" ::: "memory"); SBAR(); } while (0)

// single-plane fp16 W: W[j][i] = fp16(kernel[tri(j,i)]) for i<j else 0
__global__ void build_w_kernel(const float* __restrict__ kern,
                               unsigned short* __restrict__ W) {
  int idx = blockIdx.x * blockDim.x + threadIdx.x;
  int j = idx >> 11;
  int i = idx & (NSITE - 1);
  float v = 0.0f;
  if (i < j) v = kern[j * (j - 1) / 2 + i];
  W[idx] = f2h(v);
}

// fp16 X from f32 x, 4 elems/thread
__global__ void build_x_kernel(const float* __restrict__ x,
                               unsigned short* __restrict__ X) {
  int idx = blockIdx.x * blockDim.x + threadIdx.x;
  const float4 v = reinterpret_cast<const float4*>(x)[idx];
  reinterpret_cast<ushort4*>(X)[idx] =
      make_ushort4(f2h(v.x), f2h(v.y), f2h(v.z), f2h(v.w));
}

// 128x128 tile, 4 waves (2Mx2N), BK=32, 32x32x16 fp16 MFMA, single-plane A & W.
// LDS ring of 3 slots x (A,W) x 8KB = 48KB -> 3 blocks/CU.
// Step t consumes slot t%3; stages K-step t+2; steady wait vmcnt(4).
template <int EPI>
__global__ __launch_bounds__(256, 3) void gemm_pass(
    const unsigned short* __restrict__ A, const unsigned short* __restrict__ W,
    const float* __restrict__ x, unsigned short* __restrict__ P,
    float* __restrict__ out) {
  __shared__ unsigned short lds[3][2][BM * BK];  // 49152 B

  const int bid = blockIdx.x;
  // balanced triangular pairing: g even -> nt=15-g/2, g odd -> nt=g/2
  const int g = bid >> 7;
  const int nt = (g & 1) ? (g >> 1) : (15 - (g >> 1));
  const int mt = bid & 127;
  const int m0 = mt * BM;
  const int n0 = nt * BN;

  const int tid = threadIdx.x;
  const int lane = tid & 63;
  const int wid = tid >> 6;   // 0..3
  const int wm = wid >> 1;    // 0..1: rows wm*64..
  const int wn = wid & 1;     // 0..1: cols wn*64..
  const int l32 = lane & 31;
  const int hi2 = lane >> 5;  // 0..1

  f32x16 acc[2][2] = {};      // [mb][nb], 64 VGPRs
  f16x8 fa[2][2], fb[2][2];   // [kh][mb/nb]

  const int nkt = (n0 + BN) / BK;  // 4*(nt+1), strictly-lower-tri K cut

  auto STAGE = [&](int kidx) {
    const int slot = kidx % 3;
#pragma unroll
    for (int inst = 0; inst < 4; ++inst) {
      const int p = inst >> 1;                    // 0=A, 1=W
      const int r = (inst & 1) * 64 + (tid >> 2); // local row 0..127
      const int gch = (tid & 3) ^ ((r >> 1) & 3); // inverse swizzle on source
      const unsigned short* gp = p ? W : A;
      const int rb = p ? n0 : m0;
      const char* src =
          (const char*)(gp + (size_t)(rb + r) * NSITE + kidx * BK) + gch * 16;
      char* dst = (char*)&lds[slot][p][0] + (inst & 1) * 4096 + tid * 16;
      gload_lds16(src, dst);
    }
  };

  auto LDA_ = [&](int kh, int slot) {
#pragma unroll
    for (int mb = 0; mb < 2; ++mb) {
      const int row = wm * 64 + mb * 32 + l32;
      const int byte = row * 64 + ((((kh << 1) | hi2) ^ ((l32 >> 1) & 3)) << 4);
      fa[kh][mb] = *(const f16x8*)((const char*)&lds[slot][0][0] + byte);
    }
  };
  auto LDB_ = [&](int kh, int slot) {
#pragma unroll
    for (int nb = 0; nb < 2; ++nb) {
      const int row = wn * 64 + nb * 32 + l32;
      const int byte = row * 64 + ((((kh << 1) | hi2) ^ ((l32 >> 1) & 3)) << 4);
      fb[kh][nb] = *(const f16x8*)((const char*)&lds[slot][1][0] + byte);
    }
  };
  auto MM = [&](int kh) {  // 4 MFMA
#pragma unroll
    for (int mb = 0; mb < 2; ++mb)
#pragma unroll
      for (int nb = 0; nb < 2; ++nb)
        acc[mb][nb] = __builtin_amdgcn_mfma_f32_32x32x16_f16(fa[kh][mb], fb[kh][nb],
                                                             acc[mb][nb], 0, 0, 0);
  };

  // prologue: stage K-steps 0,1
  STAGE(0);
  STAGE(1);
  WVM(4);  // slot0 landed (slot1 may still fly)
  BAR();

  for (int t = 0; t < nkt; ++t) {
    const int slot = t % 3;
    LDB_(0, slot);               // 2 ds_read_b128
    LDA_(0, slot);               // 2
    if (t + 2 < nkt) STAGE(t + 2);  // 4 gload_lds
    LDA_(1, slot);               // 2
    LDB_(1, slot);               // 2   (lgkm outstanding 8)
    WLGKM(4);                    // kh0 frags ready
    __builtin_amdgcn_s_setprio(1);
    MM(0);
    WLGKM(0);                    // kh1 frags ready
    MM(1);
    __builtin_amdgcn_s_setprio(0);
    if (t + 1 < nkt) {
      if (t + 2 < nkt) { WVM(4); } else { WVM(0); }  // slot t+1 landed
      BAR();
    }
  }

  // C/D layout 32x32: col = lane&31, row = (reg&3)+8*(reg>>2)+4*(lane>>5)
  if (EPI == 0) {
#pragma unroll
    for (int mb = 0; mb < 2; ++mb)
#pragma unroll
      for (int nb = 0; nb < 2; ++nb)
#pragma unroll
        for (int reg = 0; reg < 16; ++reg) {
          const int row = (reg & 3) + 8 * (reg >> 2) + 4 * hi2;
          const int grow = m0 + wm * 64 + mb * 32 + row;
          const int gcol = n0 + wn * 64 + nb * 32 + l32;
          const size_t off = (size_t)grow * NSITE + gcol;
          P[off] = f2h(acc[mb][nb][reg] * x[off]);
        }
  } else {
#pragma unroll
    for (int mb = 0; mb < 2; ++mb)
#pragma unroll
      for (int reg = 0; reg < 16; ++reg) {
        const int row = (reg & 3) + 8 * (reg >> 2) + 4 * hi2;
        const int grow = m0 + wm * 64 + mb * 32 + row;
        const int gcol0 = n0 + wn * 64 + l32;
        float s = acc[mb][0][reg] * x[(size_t)grow * NSITE + gcol0] +
                  acc[mb][1][reg] * x[(size_t)grow * NSITE + gcol0 + 32];
        s += __shfl_xor(s, 1);
        s += __shfl_xor(s, 2);
        s += __shfl_xor(s, 4);
        s += __shfl_xor(s, 8);
        s += __shfl_xor(s, 16);
        if (l32 == 0) atomicAdd(&out[grow], s);
      }
  }
}

extern "C" void kernel_launch(void* const* d_in, const int* in_sizes, int n_in,
                              void* d_out, int out_size, void* d_ws, size_t ws_size,
                              hipStream_t stream) {
  const float* x = (const float*)d_in[0];
  const float* kern = (const float*)d_in[1];
  float* out = (float*)d_out;

  unsigned short* W  = (unsigned short*)d_ws;            // N*N fp16
  unsigned short* X  = W + (size_t)NSITE * NSITE;        // NS*N fp16
  unsigned short* P1 = X + (size_t)NSAMP * NSITE;        // NS*N fp16
  unsigned short* P2 = P1 + (size_t)NSAMP * NSITE;       // NS*N fp16

  hipMemsetAsync(d_out, 0, (size_t)NSAMP * sizeof(float), stream);
  build_w_kernel<<<(NSITE * NSITE) / 256, 256, 0, stream>>>(kern, W);
  build_x_kernel<<<(NSAMP * NSITE / 4) / 256, 256, 0, stream>>>(x, X);

  // pass 1: z1 = x @ W^T ; P1 = fp16(z1 * x)
  gemm_pass<0><<<NT_M * NT_N, 256, 0, stream>>>(X, W, x, P1, nullptr);
  // pass 2: z2 = P1 @ W^T ; P2 = fp16(z2 * x)
  gemm_pass<0><<<NT_M * NT_N, 256, 0, stream>>>(P1, W, x, P2, nullptr);
  // pass 3: z3 = P2 @ W^T ; out[n] = sum_j z3 * x
  gemm_pass<1><<<NT_M * NT_N, 256, 0, stream>>>(P2, W, x, nullptr, out);
}

// Round 7
// 408.275 us; speedup vs baseline: 2.8304x; 1.0215x over previous
//
#include <hip/hip_runtime.h>
#include <stdint.h>

#define NSAMP 16384
#define NSITE 2048
#define BM 128
#define BN 256
#define BK 32
#define NT_M (NSAMP / BM)   // 128
#define NT_N (NSITE / BN)   // 8

typedef _Float16 f16x8 __attribute__((ext_vector_type(8)));
typedef float f32x16 __attribute__((ext_vector_type(16)));

__device__ __forceinline__ unsigned short f2h(float f) {
  _Float16 h = (_Float16)f;
  return __builtin_bit_cast(unsigned short, h);
}
__device__ __forceinline__ float h2f(unsigned short u) {
  return (float)__builtin_bit_cast(_Float16, u);
}

__device__ __forceinline__ void gload_lds16(const void* g, void* l) {
  __builtin_amdgcn_global_load_lds(
      (const __attribute__((address_space(1))) void*)g,
      (__attribute__((address_space(3))) void*)l, 16, 0, 0);
}

#define SBAR() __builtin_amdgcn_sched_barrier(0)
#define BAR()  do { SBAR(); __builtin_amdgcn_s_barrier(); SBAR(); } while (0)
#define WLGKM(N) do { asm volatile("s_waitcnt lgkmcnt(" #N ")" ::: "memory"); SBAR(); } while (0)
#define WVM(N)   do { asm volatile("s_waitcnt vmcnt(" #N ")" ::: "memory"); SBAR(); } while (0)

// single-plane fp16 W: W[j][i] = fp16(kernel[tri(j,i)]) for i<j else 0
__global__ void build_w_kernel(const float* __restrict__ kern,
                               unsigned short* __restrict__ W) {
  int idx = blockIdx.x * blockDim.x + threadIdx.x;
  int j = idx >> 11;
  int i = idx & (NSITE - 1);
  float v = 0.0f;
  if (i < j) v = kern[j * (j - 1) / 2 + i];
  W[idx] = f2h(v);
}

// fp16 X from f32 x, 4 elems/thread
__global__ void build_x_kernel(const float* __restrict__ x,
                               unsigned short* __restrict__ X) {
  int idx = blockIdx.x * blockDim.x + threadIdx.x;
  const float4 v = reinterpret_cast<const float4*>(x)[idx];
  reinterpret_cast<ushort4*>(X)[idx] =
      make_ushort4(f2h(v.x), f2h(v.y), f2h(v.z), f2h(v.w));
}

// 128x256 block, 8 waves (2Mx4N), BK=32, 32x32x16 fp16 MFMA.
// Fragment-major LDS (zero bank conflicts): frag byte off =
// (rowblock*2 + ksub)*1024 + lane*16, lane supplies (hi,l32); staged by
// pre-scattering the per-lane GLOBAL source address (LDS dest linear).
// Ring-3 of 24KB slots (A 8KB + W 16KB) = 72KB -> 2 blocks/CU.
// Step t consumes slot t%3, stages t+2, counted wait vmcnt(3), 1 barrier/step.
template <int EPI>
__global__ __launch_bounds__(512, 4) void gemm_pass(
    const unsigned short* __restrict__ A, const unsigned short* __restrict__ W,
    const unsigned short* __restrict__ X, unsigned short* __restrict__ P,
    float* __restrict__ out) {
  __shared__ unsigned short lds[3][12288];  // 3 x 24KB

  const int bid = blockIdx.x;
  // round 1 (bid<512): nt = 7,6,5,4 ; round 2: nt = 3,2,1,0 (descending fill)
  const int g = (bid >> 7) & 3;
  const int nt = (bid >> 9) ? (3 - g) : (7 - g);
  const int mt = bid & 127;
  const int m0 = mt * BM;
  const int n0 = nt * BN;

  const int tid = threadIdx.x;
  const int lane = tid & 63;
  const int wid = tid >> 6;
  const int wm = wid >> 2;    // 0..1: rows wm*64..
  const int wn = wid & 3;     // 0..3: cols wn*64..
  const int l32 = lane & 31;
  const int hi2 = lane >> 5;
  const int lbo = lane * 16;  // linear fragment read offset

  f32x16 acc[2][2] = {};      // [mb][nb], 64 regs

  const int nkt = 8 * (nt + 1);  // strictly-lower-tri K cut

  // per-thread staging source (fragment-major scatter on the GLOBAL side)
  const int srow = ((tid >> 7) << 5) + (tid & 31);
  const int skk = (((tid >> 6) & 1) << 4) + (((tid >> 5) & 1) << 3);
  const unsigned short* sA = A + (size_t)(m0 + srow) * NSITE + skk;
  const unsigned short* sB0 = W + (size_t)(n0 + srow) * NSITE + skk;
  const unsigned short* sB1 = W + (size_t)(n0 + 128 + srow) * NSITE + skk;

  auto STAGE = [&](int kidx, int slot) {
    char* Ls = (char*)&lds[slot][0];
    const int ko = kidx * BK;
    gload_lds16(sA + ko, Ls + tid * 16);
    gload_lds16(sB0 + ko, Ls + 8192 + tid * 16);
    gload_lds16(sB1 + ko, Ls + 16384 + tid * 16);
  };

  STAGE(0, 0);
  STAGE(1, 1);
  WVM(3);  // slot0 landed (slot1 may still fly)
  BAR();

  int slot = 0, slot2 = 2;
  for (int t = 0; t < nkt; ++t) {
    const char* Ls = (const char*)&lds[slot][0];
    f16x8 a0, a1, b0, b1, a2, a3, b2, b3;
    // ksub0 fragments: off = (rowblock*2 + 0)*1024
    a0 = *(const f16x8*)(Ls + (wm * 4 + 0) * 1024 + lbo);        // mb0 ksub0
    a1 = *(const f16x8*)(Ls + (wm * 4 + 2) * 1024 + lbo);        // mb1 ksub0
    b0 = *(const f16x8*)(Ls + 8192 + (wn * 4 + 0) * 1024 + lbo); // nb0 ksub0
    b1 = *(const f16x8*)(Ls + 8192 + (wn * 4 + 2) * 1024 + lbo); // nb1 ksub0
    SBAR();
    // ksub1 fragments: off = (rowblock*2 + 1)*1024
    a2 = *(const f16x8*)(Ls + (wm * 4 + 1) * 1024 + lbo);
    a3 = *(const f16x8*)(Ls + (wm * 4 + 3) * 1024 + lbo);
    b2 = *(const f16x8*)(Ls + 8192 + (wn * 4 + 1) * 1024 + lbo);
    b3 = *(const f16x8*)(Ls + 8192 + (wn * 4 + 3) * 1024 + lbo);
    SBAR();
    if (t + 2 < nkt) STAGE(t + 2, slot2);
    WLGKM(4);  // ksub0 group done
    __builtin_amdgcn_s_setprio(1);
    acc[0][0] = __builtin_amdgcn_mfma_f32_32x32x16_f16(a0, b0, acc[0][0], 0, 0, 0);
    acc[0][1] = __builtin_amdgcn_mfma_f32_32x32x16_f16(a0, b1, acc[0][1], 0, 0, 0);
    acc[1][0] = __builtin_amdgcn_mfma_f32_32x32x16_f16(a1, b0, acc[1][0], 0, 0, 0);
    acc[1][1] = __builtin_amdgcn_mfma_f32_32x32x16_f16(a1, b1, acc[1][1], 0, 0, 0);
    WLGKM(0);  // ksub1 group done
    acc[0][0] = __builtin_amdgcn_mfma_f32_32x32x16_f16(a2, b2, acc[0][0], 0, 0, 0);
    acc[0][1] = __builtin_amdgcn_mfma_f32_32x32x16_f16(a2, b3, acc[0][1], 0, 0, 0);
    acc[1][0] = __builtin_amdgcn_mfma_f32_32x32x16_f16(a3, b2, acc[1][0], 0, 0, 0);
    acc[1][1] = __builtin_amdgcn_mfma_f32_32x32x16_f16(a3, b3, acc[1][1], 0, 0, 0);
    __builtin_amdgcn_s_setprio(0);
    if (t + 1 < nkt) {
      if (t + 2 < nkt) { WVM(3); } else { WVM(0); }  // slot t+1 landed
      BAR();
    }
    slot = (slot == 2) ? 0 : slot + 1;
    slot2 = (slot2 == 2) ? 0 : slot2 + 1;
  }

  // C/D layout 32x32: col = lane&31, row = (reg&3)+8*(reg>>2)+4*(lane>>5)
  if (EPI == 0) {
#pragma unroll
    for (int m = 0; m < 2; ++m)
#pragma unroll
      for (int n = 0; n < 2; ++n)
#pragma unroll
        for (int r = 0; r < 16; ++r) {
          const int row = (r & 3) + 8 * (r >> 2) + 4 * hi2;
          const int grow = m0 + wm * 64 + m * 32 + row;
          const int gcol = n0 + wn * 64 + n * 32 + l32;
          const size_t off = (size_t)grow * NSITE + gcol;
          P[off] = f2h(acc[m][n][r] * h2f(X[off]));
        }
  } else {
#pragma unroll
    for (int m = 0; m < 2; ++m)
#pragma unroll
      for (int r = 0; r < 16; ++r) {
        const int row = (r & 3) + 8 * (r >> 2) + 4 * hi2;
        const int grow = m0 + wm * 64 + m * 32 + row;
        const size_t base = (size_t)grow * NSITE + n0 + wn * 64 + l32;
        float s = acc[m][0][r] * h2f(X[base]) + acc[m][1][r] * h2f(X[base + 32]);
        s += __shfl_xor(s, 1);
        s += __shfl_xor(s, 2);
        s += __shfl_xor(s, 4);
        s += __shfl_xor(s, 8);
        s += __shfl_xor(s, 16);
        if (l32 == 0) atomicAdd(&out[grow], s);
      }
  }
}

extern "C" void kernel_launch(void* const* d_in, const int* in_sizes, int n_in,
                              void* d_out, int out_size, void* d_ws, size_t ws_size,
                              hipStream_t stream) {
  const float* x = (const float*)d_in[0];
  const float* kern = (const float*)d_in[1];
  float* out = (float*)d_out;

  unsigned short* W  = (unsigned short*)d_ws;            // N*N fp16
  unsigned short* X  = W + (size_t)NSITE * NSITE;        // NS*N fp16
  unsigned short* P1 = X + (size_t)NSAMP * NSITE;        // NS*N fp16
  unsigned short* P2 = P1 + (size_t)NSAMP * NSITE;       // NS*N fp16

  hipMemsetAsync(d_out, 0, (size_t)NSAMP * sizeof(float), stream);
  build_w_kernel<<<(NSITE * NSITE) / 256, 256, 0, stream>>>(kern, W);
  build_x_kernel<<<(NSAMP * NSITE / 4) / 256, 256, 0, stream>>>(x, X);

  // pass 1: z1 = x @ W^T ; P1 = fp16(z1 * x)
  gemm_pass<0><<<NT_M * NT_N, 512, 0, stream>>>(X, W, X, P1, nullptr);
  // pass 2: z2 = P1 @ W^T ; P2 = fp16(z2 * x)
  gemm_pass<0><<<NT_M * NT_N, 512, 0, stream>>>(P1, W, X, P2, nullptr);
  // pass 3: z3 = P2 @ W^T ; out[n] = sum_j z3 * x
  gemm_pass<1><<<NT_M * NT_N, 512, 0, stream>>>(P2, W, X, nullptr, out);
}